// Round 17
// baseline (183.665 us; speedup 1.0000x reference)
//
#include <hip/hip_runtime.h>
#include <hip/hip_fp16.h>

#define B_ 2
#define CX 64
#define HH 192
#define WW 192
#define HW (HH*WW)
#define HS 48
#define WS 48
#define HWS (HS*WS)
#define CE 160
#define C4 432
#define DG_ 16
#define COUT_D 128
#define VSTR 108   // val row stride in u16: 54 words, gcd(54,32)=2 -> 16 banks (4-way)

typedef _Float16 f16x8 __attribute__((ext_vector_type(8)));
typedef float f32x4 __attribute__((ext_vector_type(4)));
typedef unsigned short u16;

__device__ __forceinline__ float tanh_fast(float v) {
    float e = __expf(2.f * v);
    return 1.f - 2.f * __builtin_amdgcn_rcpf(e + 1.f);
}
__device__ __forceinline__ float sigmoid_fast(float s) {
    return __builtin_amdgcn_rcpf(1.f + __expf(-s));
}

// ---------------- mega-prep: wq1..wq4 (fp16) + wA + xg transpose + pool (one launch) ----------------
__device__ __forceinline__ void prep_wq_f16(const float* __restrict__ w, u16* __restrict__ wq,
                                            int i, int OC, int OCP, int CIN) {
    int ic = i % CIN; int rest = i / CIN;
    int oc = rest % OCP; int q = rest / OCP;
    float v = (oc < OC) ? w[((size_t)oc * CIN + ic) * 9 + q] : 0.f;
    wq[i] = __half_as_ushort(__float2half_rn(v));
}

__global__ void mega_prep_kernel(const float* __restrict__ w1, const float* __restrict__ w2,
                                 const float* __restrict__ w3, const float* __restrict__ w4,
                                 const float* __restrict__ wgt,
                                 const float* __restrict__ x, const float* __restrict__ flow,
                                 const float* __restrict__ addf,
                                 u16* __restrict__ wq1, u16* __restrict__ wq2,
                                 u16* __restrict__ wq3, u16* __restrict__ wq4,
                                 u16* __restrict__ wA,
                                 u16* __restrict__ xg, u16* __restrict__ pt) {
    int bid = blockIdx.x, t = threadIdx.x;
    if (bid < 360)  { prep_wq_f16(w1, wq1, bid * 256 + t, 64, 64, 160); return; }
    if (bid < 504)  { prep_wq_f16(w2, wq2, (bid - 360) * 256 + t, 64, 64, 64); return; }
    if (bid < 648)  { prep_wq_f16(w3, wq3, (bid - 504) * 256 + t, 64, 64, 64); return; }
    if (bid < 1656) { prep_wq_f16(w4, wq4, (bid - 648) * 256 + t, 432, 448, 64); return; }
    if (bid < 2424) {
        // wA fp16: [o][g*96 + tap*8 + c], taps 9..11 = 0
        int i = (bid - 1656) * 256 + t;              // 128*1536 = 768*256
        int o = i / 1536, col = i - o * 1536;
        int g = col / 96, r = col - g * 96;
        int tap = r >> 3, c = r & 7;
        float v = (tap < 9) ? wgt[(size_t)o * 1152 + (g * 8 + c) * 9 + tap] : 0.f;
        wA[i] = __half_as_ushort(__float2half_rn(v));
        return;
    }
    if (bid < 7032) {
        int i = (bid - 2424) * 256 + t;              // 2*16*36864
        int p = i % HW;
        int g = (i / HW) % DG_;
        int b = i / (HW * DG_);
        const float* xb = x    + ((size_t)(b * CX + g * 4)) * HW + p;
        const float* ab = addf + ((size_t)(b * CX + g * 4)) * HW + p;
        __half2 h[4];
        h[0].x = __float2half_rn(xb[0]);      h[0].y = __float2half_rn(xb[HW]);
        h[1].x = __float2half_rn(xb[2 * HW]); h[1].y = __float2half_rn(xb[3 * HW]);
        h[2].x = __float2half_rn(ab[0]);      h[2].y = __float2half_rn(ab[HW]);
        h[3].x = __float2half_rn(ab[2 * HW]); h[3].y = __float2half_rn(ab[3 * HW]);
        *reinterpret_cast<uint4*>(&xg[(size_t)i * 8]) = *reinterpret_cast<uint4*>(h);
    } else {
        int i = (bid - 7032) * 256 + t;              // 737280
        int xs = i % WS, ys = (i / WS) % HS, c = (i / HWS) % CE, b = i / (HWS * CE);
        const float* src;
        if (c < 64)      src = x    + (size_t)(b * 64 + c) * HW;
        else if (c < 96) src = flow + (size_t)(b * 32 + (c - 64)) * HW;
        else             src = addf + (size_t)(b * 64 + (c - 96)) * HW;
        const float4* s4 = reinterpret_cast<const float4*>(src + (ys * 4) * WW + xs * 4);
        float sum = 0.f;
#pragma unroll
        for (int r = 0; r < 4; ++r) {
            float4 v = s4[r * (WW / 4)];
            sum += v.x + v.y + v.z + v.w;
        }
        pt[((size_t)(b * HWS + ys * WS + xs)) * CE + c] =
            __half_as_ushort(__float2half_rn(sum * (1.f / 16.f)));
    }
}

// ---------------- 4-way K-split fp16 MFMA 3x3 conv (64 oc), LDS-staged input tile ----------------
template<int CIN, int U0, int U1, int U2, int UT, bool LRELU>
__global__ __launch_bounds__(1024) void conv_ks(const u16* __restrict__ in_t,
                                                const u16* __restrict__ wq,
                                                const float* __restrict__ bias,
                                                u16* __restrict__ out_t) {
    constexpr int CP = CIN + 8;
    __shared__ u16 tile_in[36 * CP];
    __shared__ float red[3 * 4 * 256];
    const int t = threadIdx.x;
    const int w = t >> 6;
    const int ocgrp = w & 3, ks = w >> 2;
    const int lane = t & 63;
    const int l15 = t & 15, l4 = (t >> 4) & 3;
    const int tile = blockIdx.x;
    const int ty0 = (tile / 12) * 4, tx0 = (tile % 12) * 4;
    const int b = blockIdx.z;
    const int ocb = ocgrp * 16;
    const int py = ty0 + (l15 >> 2), pxx = tx0 + (l15 & 3);
    const u16* inb = in_t + (size_t)b * HWS * CIN;

    for (int i = t; i < 36 * (CIN / 8); i += 1024) {
        int c8 = i % (CIN / 8); int spx = i / (CIN / 8);
        int gy = ty0 - 1 + spx / 6, gx = tx0 - 1 + spx % 6;
        uint4 v = make_uint4(0, 0, 0, 0);
        if ((unsigned)gy < 48u && (unsigned)gx < 48u)
            v = *reinterpret_cast<const uint4*>(&inb[(size_t)(gy * 48 + gx) * CIN + c8 * 8]);
        *reinterpret_cast<uint4*>(&tile_in[spx * CP + c8 * 8]) = v;
    }
    __syncthreads();

    f32x4 acc = {0, 0, 0, 0};
    constexpr int KB = CIN / 32;
    const int lpy = l15 >> 2, lpx = l15 & 3;

    __builtin_amdgcn_s_setprio(1);
#define CONV_BODY(US, UE)                                                             \
    _Pragma("unroll")                                                                 \
    for (int u = (US); u < (UE); ++u) {                                               \
        const int q = u / KB, kb = u % KB;                                            \
        const int spx = (lpy + q / 3) * 6 + (lpx + q % 3);                            \
        f16x8 B = *reinterpret_cast<const f16x8*>(&tile_in[spx * CP + kb * 32 + l4 * 8]); \
        f16x8 A = *reinterpret_cast<const f16x8*>(                                    \
            wq + ((size_t)q * 64 + ocb + l15) * CIN + kb * 32 + l4 * 8);              \
        acc = __builtin_amdgcn_mfma_f32_16x16x32_f16(A, B, acc, 0, 0, 0);             \
    }
    if (ks == 0)      { CONV_BODY(0,  U0) }
    else if (ks == 1) { CONV_BODY(U0, U1) }
    else if (ks == 2) { CONV_BODY(U1, U2) }
    else              { CONV_BODY(U2, UT) }
#undef CONV_BODY
    __builtin_amdgcn_s_setprio(0);

    if (ks) {
#pragma unroll
        for (int r = 0; r < 4; ++r)
            red[((ks - 1) * 4 + ocgrp) * 256 + r * 64 + lane] = acc[r];
    }
    __syncthreads();
    if (!ks) {
#pragma unroll
        for (int r = 0; r < 4; ++r) {
            float v = acc[r];
#pragma unroll
            for (int j = 0; j < 3; ++j)
                v += red[(j * 4 + ocgrp) * 256 + r * 64 + lane];
            int oc = ocb + l4 * 4 + r;
            v += bias[oc];
            if (LRELU) v = (v >= 0.f) ? v : 0.2f * v;
            out_t[((size_t)(b * HWS + py * 48 + pxx)) * 64 + oc] =
                __half_as_ushort(__float2half_rn(v));
        }
    }
}

// ---------------- fp16 MFMA 3x3 conv (conv4: 432 oc, f32 out), 4 waves, LDS-staged tile ----------------
template<int CIN, int OC, int OCP, bool LRELU>
__global__ __launch_bounds__(256) void conv_mfma(const u16* __restrict__ in_t,
                                                 const u16* __restrict__ wq,
                                                 const float* __restrict__ bias,
                                                 float* __restrict__ out_f) {
    constexpr int CP = CIN + 8;
    __shared__ u16 tile_in[36 * CP];
    const int t = threadIdx.x;
    const int wv = __builtin_amdgcn_readfirstlane(t >> 6);
    const int l15 = t & 15, l4 = (t >> 4) & 3;
    const int tile = blockIdx.x;
    const int ty0 = (tile / 12) * 4, tx0 = (tile % 12) * 4;
    const int ocb = blockIdx.y * 64 + wv * 16;
    const int b = blockIdx.z;
    const int py = ty0 + (l15 >> 2), pxx = tx0 + (l15 & 3);
    const u16* inb = in_t + (size_t)b * HWS * CIN;

    for (int i = t; i < 36 * (CIN / 8); i += 256) {
        int c8 = i % (CIN / 8); int spx = i / (CIN / 8);
        int gy = ty0 - 1 + spx / 6, gx = tx0 - 1 + spx % 6;
        uint4 v = make_uint4(0, 0, 0, 0);
        if ((unsigned)gy < 48u && (unsigned)gx < 48u)
            v = *reinterpret_cast<const uint4*>(&inb[(size_t)(gy * 48 + gx) * CIN + c8 * 8]);
        *reinterpret_cast<uint4*>(&tile_in[spx * CP + c8 * 8]) = v;
    }
    __syncthreads();

    f32x4 acc = {0, 0, 0, 0};
    const int lpy = l15 >> 2, lpx = l15 & 3;
    __builtin_amdgcn_s_setprio(1);
#pragma unroll
    for (int q = 0; q < 9; ++q) {
        const int spx = (lpy + q / 3) * 6 + (lpx + q % 3);
#pragma unroll
        for (int kb = 0; kb < CIN / 32; ++kb) {
            f16x8 B = *reinterpret_cast<const f16x8*>(&tile_in[spx * CP + kb * 32 + l4 * 8]);
            f16x8 A = *reinterpret_cast<const f16x8*>(
                wq + ((size_t)q * OCP + ocb + l15) * CIN + kb * 32 + l4 * 8);
            acc = __builtin_amdgcn_mfma_f32_16x16x32_f16(A, B, acc, 0, 0, 0);
        }
    }
    __builtin_amdgcn_s_setprio(0);
#pragma unroll
    for (int r = 0; r < 4; ++r) {
        int oc = ocb + l4 * 4 + r;
        float v = acc[r] + ((oc < OC) ? bias[oc] : 0.f);
        if (LRELU) v = (v >= 0.f) ? v : 0.2f * v;
        if (oc < OC) out_f[((size_t)(b * OC + oc)) * HWS + py * 48 + pxx] = v;
    }
}

// ---------------- deform v13: R15 structure, val stride 104->108 u16 (bank de-alias, uint2 access) ----------------
__global__ __launch_bounds__(512) void deform_mfma(
    const u16* __restrict__ xg, const float* __restrict__ flow,
    const float* __restrict__ a4, const u16* __restrict__ wA,
    const float* __restrict__ bias, float* __restrict__ out)
{
    __shared__ u16 val[2][64 * VSTR];                // fp16 [pixel][ck], stride 108 (16-bank spread)
    __shared__ float a4t[2][27 * 16];
    __shared__ float flds[2][128];
    __shared__ float rw[4][64];
    __shared__ int rb[64];
    const int t = threadIdx.x;
    const int traw = blockIdx.x;
    const int tile = (traw & 7) * 72 + (traw >> 3);
    const int b = blockIdx.y;
    const int ty0 = (tile / 24) * 8, tx0 = (tile % 24) * 8;
    const int lane = t & 63;
    const int og = __builtin_amdgcn_readfirstlane(t >> 6);
    const int l15 = lane & 15, l4 = lane >> 4;
    const int ys0 = (ty0 >> 2) - 1, xs0 = (tx0 >> 2) - 1;

    f32x4 acc[4];
#pragma unroll
    for (int n = 0; n < 4; ++n) acc[n] = (f32x4){0.f, 0.f, 0.f, 0.f};

    int sg_y = 0, sg_x = 0, sg_ch = 0;
    if (t < 432) {
        int ch = t >> 4, idx = t & 15;
        sg_y = min(max(ys0 + (idx >> 2), 0), 47);
        sg_x = min(max(xs0 + (idx & 3), 0), 47);
        sg_ch = ch;
    }

    if (t < 64) {
        int p = t;
        int y = ty0 + (p >> 3), xx = tx0 + (p & 7);
        float ysf = fminf(fmaxf((y + 0.5f) * 0.25f - 0.5f, 0.f), 47.f);
        float xsf = fminf(fmaxf((xx + 0.5f) * 0.25f - 0.5f, 0.f), 47.f);
        int ry0 = (int)ysf, rx0 = (int)xsf;
        float fy = ysf - (float)ry0, fx = xsf - (float)rx0;
        rb[p] = (ry0 - ys0) * 4 + (rx0 - xs0);
        rw[0][p] = (1.f - fy) * (1.f - fx);
        rw[1][p] = (1.f - fy) * fx;
        rw[2][p] = fy * (1.f - fx);
        rw[3][p] = fy * fx;
    }
    // zero K-pad (cols 72..95) of both val buffers via uint2
    if (t < 384) {
        int bb = (t >= 192) ? 1 : 0; int j = t - bb * 192;
        int row = j / 3, un = 9 + j % 3;
        uint2 z = make_uint2(0, 0);
        *reinterpret_cast<uint2*>(&val[bb][row * VSTR + un * 8]) = z;
        *reinterpret_cast<uint2*>(&val[bb][row * VSTR + un * 8 + 4]) = z;
    }

    const float* a4b = a4 + (size_t)b * C4 * HWS;
    const float* flb = flow + (size_t)b * 32 * HW;
    const u16* xgb0 = xg + (size_t)b * DG_ * HW * 8;

#define STAGE_LOAD(gg, ra, rf) do {                                                 \
    const int gk = (gg);                                                            \
    if (t < 432) {                                                                  \
        int a4ch = (sg_ch < 18) ? (gk * 18 + sg_ch) : (288 + gk * 9 + (sg_ch - 18));\
        (ra) = a4b[(size_t)a4ch * HWS + sg_y * 48 + sg_x];                          \
    }                                                                               \
    if (t < 128) {                                                                  \
        int comp = t >> 6, p = t & 63;                                              \
        int y = ty0 + (p >> 3), xx = tx0 + (p & 7);                                 \
        (rf) = flb[(size_t)(2 * gk + 1 - comp) * HW + y * WW + xx];                 \
    }                                                                               \
} while (0)

#define STAGE_WRITE(bb, ra, rf) do {                                                \
    if (t < 432) a4t[bb][t] = (ra);                                                 \
    if (t < 128) flds[bb][t] = (rf);                                                \
} while (0)

#define PH12(gg, bb) do {                                                           \
    const u16* xgb = xgb0 + (size_t)(gg) * HW * 8;                                  \
    for (int i = t; i < 576; i += 512) {                                            \
        int k = i >> 6, p = i & 63;                                                 \
        int y = ty0 + (p >> 3), xx = tx0 + (p & 7);                                 \
        int base = rb[p];                                                           \
        float r00 = rw[0][p], r01 = rw[1][p], r10 = rw[2][p], r11 = rw[3][p];       \
        const float* A = &a4t[bb][0];                                               \
        float sdy = A[(2*k)*16+base]*r00 + A[(2*k)*16+base+1]*r01                   \
                  + A[(2*k)*16+base+4]*r10 + A[(2*k)*16+base+5]*r11;                \
        float sdx = A[(2*k+1)*16+base]*r00 + A[(2*k+1)*16+base+1]*r01               \
                  + A[(2*k+1)*16+base+4]*r10 + A[(2*k+1)*16+base+5]*r11;            \
        float sm  = A[(18+k)*16+base]*r00 + A[(18+k)*16+base+1]*r01                 \
                  + A[(18+k)*16+base+4]*r10 + A[(18+k)*16+base+5]*r11;              \
        float dyv = 5.f * tanh_fast(sdy) + flds[bb][p];                             \
        float dxv = 5.f * tanh_fast(sdx) + flds[bb][64 + p];                        \
        float m = sigmoid_fast(sm);                                                 \
        float fpy = (float)(y + (k / 3) - 1) + dyv;                                 \
        float fpx = (float)(xx + (k % 3) - 1) + dxv;                                \
        float y0f = floorf(fpy), x0f = floorf(fpx);                                 \
        int gy0 = (int)y0f, gx0 = (int)x0f;                                         \
        int gy1 = gy0 + 1, gx1 = gx0 + 1;                                           \
        float wy = fpy - y0f, wx = fpx - x0f;                                       \
        bool by0 = (unsigned)gy0 < (unsigned)HH, by1 = (unsigned)gy1 < (unsigned)HH;\
        bool bx0 = (unsigned)gx0 < (unsigned)WW, bx1 = (unsigned)gx1 < (unsigned)WW;\
        int y0c = min(max(gy0, 0), HH - 1), y1c = min(max(gy1, 0), HH - 1);         \
        int x0c = min(max(gx0, 0), WW - 1), x1c = min(max(gx1, 0), WW - 1);         \
        float w00 = (by0 && bx0) ? (1.f - wy) * (1.f - wx) * m : 0.f;               \
        float w01 = (by0 && bx1) ? (1.f - wy) * wx * m : 0.f;                       \
        float w10 = (by1 && bx0) ? wy * (1.f - wx) * m : 0.f;                       \
        float w11 = (by1 && bx1) ? wy * wx * m : 0.f;                               \
        uint4 v00 = *reinterpret_cast<const uint4*>(&xgb[(size_t)(y0c * WW + x0c) * 8]); \
        uint4 v01 = *reinterpret_cast<const uint4*>(&xgb[(size_t)(y0c * WW + x1c) * 8]); \
        uint4 v10 = *reinterpret_cast<const uint4*>(&xgb[(size_t)(y1c * WW + x0c) * 8]); \
        uint4 v11 = *reinterpret_cast<const uint4*>(&xgb[(size_t)(y1c * WW + x1c) * 8]); \
        const __half2* h00 = reinterpret_cast<const __half2*>(&v00);                \
        const __half2* h01 = reinterpret_cast<const __half2*>(&v01);                \
        const __half2* h10 = reinterpret_cast<const __half2*>(&v10);                \
        const __half2* h11 = reinterpret_cast<const __half2*>(&v11);                \
        __half hw00 = __float2half_rn(w00), hw01 = __float2half_rn(w01);            \
        __half hw10 = __float2half_rn(w10), hw11 = __float2half_rn(w11);            \
        __half2 W00{hw00, hw00}, W01{hw01, hw01}, W10{hw10, hw10}, W11{hw11, hw11}; \
        union { __half2 h2[4]; uint2 u2[2]; } uu;                                   \
        _Pragma("unroll")                                                           \
        for (int cc = 0; cc < 4; ++cc)                                              \
            uu.h2[cc] = __hfma2(h00[cc], W00, __hfma2(h01[cc], W01,                 \
                        __hfma2(h10[cc], W10, __hmul2(h11[cc], W11))));             \
        *reinterpret_cast<uint2*>(&val[bb][p * VSTR + k * 8]) = uu.u2[0];           \
        *reinterpret_cast<uint2*>(&val[bb][p * VSTR + k * 8 + 4]) = uu.u2[1];       \
    }                                                                               \
} while (0)

    {
        float ra = 0.f, rf = 0.f;
        STAGE_LOAD(0, ra, rf);
        STAGE_WRITE(0, ra, rf);
    }
    __syncthreads();

    for (int g = 0; g < DG_; ++g) {
        const int buf = g & 1;
        float ra = 0.f, rf = 0.f;
        if (g < 15) STAGE_LOAD(g + 1, ra, rf);
        PH12(g, buf);
        if (g < 15) STAGE_WRITE(buf ^ 1, ra, rf);
        __syncthreads();
        const u16* wg = wA + (size_t)(og * 16) * 1536 + g * 96;
        __builtin_amdgcn_s_setprio(1);
#pragma unroll
        for (int kb = 0; kb < 3; ++kb) {
            f16x8 a = *reinterpret_cast<const f16x8*>(wg + (size_t)l15 * 1536 + kb * 32 + l4 * 8);
#pragma unroll
            for (int nf = 0; nf < 4; ++nf) {
                int row = nf * 16 + l15;
                union { uint2 u2[2]; f16x8 v; } bf;
                bf.u2[0] = *reinterpret_cast<const uint2*>(&val[buf][row * VSTR + kb * 32 + l4 * 8]);
                bf.u2[1] = *reinterpret_cast<const uint2*>(&val[buf][row * VSTR + kb * 32 + l4 * 8 + 4]);
                acc[nf] = __builtin_amdgcn_mfma_f32_16x16x32_f16(a, bf.v, acc[nf], 0, 0, 0);
            }
        }
        __builtin_amdgcn_s_setprio(0);
    }
#undef STAGE_LOAD
#undef STAGE_WRITE
#undef PH12
#pragma unroll
    for (int nf = 0; nf < 4; ++nf) {
        int pix = nf * 16 + l15;
        int py = ty0 + (pix >> 3), px = tx0 + (pix & 7);
#pragma unroll
        for (int r = 0; r < 4; ++r) {
            int o = og * 16 + l4 * 4 + r;
            out[((size_t)(b * COUT_D + o) * HH + py) * WW + px] = acc[nf][r] + bias[o];
        }
    }
}

extern "C" void kernel_launch(void* const* d_in, const int* in_sizes, int n_in,
                              void* d_out, int out_size, void* d_ws, size_t ws_size,
                              hipStream_t stream) {
    const float* x    = (const float*)d_in[0];
    const float* flow = (const float*)d_in[1];
    const float* addf = (const float*)d_in[2];
    const float* w1   = (const float*)d_in[3];
    const float* b1   = (const float*)d_in[4];
    const float* w2   = (const float*)d_in[5];
    const float* b2   = (const float*)d_in[6];
    const float* w3   = (const float*)d_in[7];
    const float* b3   = (const float*)d_in[8];
    const float* w4   = (const float*)d_in[9];
    const float* b4   = (const float*)d_in[10];
    const float* wgt  = (const float*)d_in[11];
    const float* bias = (const float*)d_in[12];
    float* out = (float*)d_out;
    float* ws = (float*)d_ws;

    u16*  pool_t = (u16*)ws;                         // 737,280 u16 (fp16)
    u16*  c1     = pool_t + 737280;                  // 294,912 u16
    u16*  c2     = c1 + 294912;                      // 294,912 u16
    u16*  c3     = c1;                               // alias (c1 dead after conv2)
    float* a4    = (float*)(c2 + 294912);            // 1,990,656 f32
    u16*  wq1    = (u16*)(a4 + 1990656);             // 92,160 u16
    u16*  wq2    = wq1 + 92160;                      // 36,864
    u16*  wq3    = wq2 + 36864;                      // 36,864
    u16*  wq4    = wq3 + 36864;                      // 258,048
    u16*  wA     = wq4 + 258048;                     // 196,608 (fp16)
    u16*  xg     = wA + 196608;                      // 9,437,184 (fp16)

    mega_prep_kernel<<<9912, 256, 0, stream>>>(w1, w2, w3, w4, wgt, x, flow, addf,
                                               wq1, wq2, wq3, wq4, wA, xg, pool_t);

    conv_ks<160, 12, 23, 34, 45, true><<<dim3(144, 1, 2), 1024, 0, stream>>>(pool_t, wq1, b1, c1);
    conv_ks<64,  5,  10, 14, 18, true><<<dim3(144, 1, 2), 1024, 0, stream>>>(c1, wq2, b2, c2);
    conv_ks<64,  5,  10, 14, 18, true><<<dim3(144, 1, 2), 1024, 0, stream>>>(c2, wq3, b3, c3);
    conv_mfma<64, 432, 448, false><<<dim3(144, 7, 2), 256, 0, stream>>>(c3, wq4, b4, a4);

    deform_mfma<<<dim3(576, 2), 512, 0, stream>>>(xg, flow, a4, wA, bias, out);
}

// Round 18
// 180.735 us; speedup vs baseline: 1.0162x; 1.0162x over previous
//
#include <hip/hip_runtime.h>
#include <hip/hip_fp16.h>

#define B_ 2
#define CX 64
#define HH 192
#define WW 192
#define HW (HH*WW)
#define HS 48
#define WS 48
#define HWS (HS*WS)
#define CE 160
#define C4 432
#define DG_ 16
#define COUT_D 128
#define VSTR 108   // val row stride in u16: 54 words, gcd(54,32)=2 -> 16 banks (4-way)

typedef _Float16 f16x8 __attribute__((ext_vector_type(8)));
typedef float f32x4 __attribute__((ext_vector_type(4)));
typedef unsigned short u16;

__device__ __forceinline__ float tanh_fast(float v) {
    float e = __expf(2.f * v);
    return 1.f - 2.f * __builtin_amdgcn_rcpf(e + 1.f);
}
__device__ __forceinline__ float sigmoid_fast(float s) {
    return __builtin_amdgcn_rcpf(1.f + __expf(-s));
}

// ---------------- mega-prep: wq1..wq4 (fp16) + wA + xg transpose + pool (one launch) ----------------
__device__ __forceinline__ void prep_wq_f16(const float* __restrict__ w, u16* __restrict__ wq,
                                            int i, int OC, int OCP, int CIN) {
    int ic = i % CIN; int rest = i / CIN;
    int oc = rest % OCP; int q = rest / OCP;
    float v = (oc < OC) ? w[((size_t)oc * CIN + ic) * 9 + q] : 0.f;
    wq[i] = __half_as_ushort(__float2half_rn(v));
}

__global__ void mega_prep_kernel(const float* __restrict__ w1, const float* __restrict__ w2,
                                 const float* __restrict__ w3, const float* __restrict__ w4,
                                 const float* __restrict__ wgt,
                                 const float* __restrict__ x, const float* __restrict__ flow,
                                 const float* __restrict__ addf,
                                 u16* __restrict__ wq1, u16* __restrict__ wq2,
                                 u16* __restrict__ wq3, u16* __restrict__ wq4,
                                 u16* __restrict__ wA,
                                 u16* __restrict__ xg, u16* __restrict__ pt) {
    int bid = blockIdx.x, t = threadIdx.x;
    if (bid < 360)  { prep_wq_f16(w1, wq1, bid * 256 + t, 64, 64, 160); return; }
    if (bid < 504)  { prep_wq_f16(w2, wq2, (bid - 360) * 256 + t, 64, 64, 64); return; }
    if (bid < 648)  { prep_wq_f16(w3, wq3, (bid - 504) * 256 + t, 64, 64, 64); return; }
    if (bid < 1656) { prep_wq_f16(w4, wq4, (bid - 648) * 256 + t, 432, 448, 64); return; }
    if (bid < 2424) {
        // wA fp16: [o][g*96 + tap*8 + c], taps 9..11 = 0
        int i = (bid - 1656) * 256 + t;              // 128*1536 = 768*256
        int o = i / 1536, col = i - o * 1536;
        int g = col / 96, r = col - g * 96;
        int tap = r >> 3, c = r & 7;
        float v = (tap < 9) ? wgt[(size_t)o * 1152 + (g * 8 + c) * 9 + tap] : 0.f;
        wA[i] = __half_as_ushort(__float2half_rn(v));
        return;
    }
    if (bid < 7032) {
        int i = (bid - 2424) * 256 + t;              // 2*16*36864
        int p = i % HW;
        int g = (i / HW) % DG_;
        int b = i / (HW * DG_);
        const float* xb = x    + ((size_t)(b * CX + g * 4)) * HW + p;
        const float* ab = addf + ((size_t)(b * CX + g * 4)) * HW + p;
        __half2 h[4];
        h[0].x = __float2half_rn(xb[0]);      h[0].y = __float2half_rn(xb[HW]);
        h[1].x = __float2half_rn(xb[2 * HW]); h[1].y = __float2half_rn(xb[3 * HW]);
        h[2].x = __float2half_rn(ab[0]);      h[2].y = __float2half_rn(ab[HW]);
        h[3].x = __float2half_rn(ab[2 * HW]); h[3].y = __float2half_rn(ab[3 * HW]);
        *reinterpret_cast<uint4*>(&xg[(size_t)i * 8]) = *reinterpret_cast<uint4*>(h);
    } else {
        int i = (bid - 7032) * 256 + t;              // 737280
        int xs = i % WS, ys = (i / WS) % HS, c = (i / HWS) % CE, b = i / (HWS * CE);
        const float* src;
        if (c < 64)      src = x    + (size_t)(b * 64 + c) * HW;
        else if (c < 96) src = flow + (size_t)(b * 32 + (c - 64)) * HW;
        else             src = addf + (size_t)(b * 64 + (c - 96)) * HW;
        const float4* s4 = reinterpret_cast<const float4*>(src + (ys * 4) * WW + xs * 4);
        float sum = 0.f;
#pragma unroll
        for (int r = 0; r < 4; ++r) {
            float4 v = s4[r * (WW / 4)];
            sum += v.x + v.y + v.z + v.w;
        }
        pt[((size_t)(b * HWS + ys * WS + xs)) * CE + c] =
            __half_as_ushort(__float2half_rn(sum * (1.f / 16.f)));
    }
}

// ---------------- 4-way K-split fp16 MFMA 3x3 conv, 8 waves = 2 ocgrp x 4 ksplit,
// grid.y = ocpair (2) -> 576 blocks (2.25/CU vs 1.1 before) ----------------
template<int CIN, int U0, int U1, int U2, int UT, bool LRELU>
__global__ __launch_bounds__(512) void conv_ks(const u16* __restrict__ in_t,
                                               const u16* __restrict__ wq,
                                               const float* __restrict__ bias,
                                               u16* __restrict__ out_t) {
    constexpr int CP = CIN + 8;
    __shared__ u16 tile_in[36 * CP];
    __shared__ float red[3 * 2 * 256];               // [ks-1][ocgrp_local][r*64+lane]
    const int t = threadIdx.x;
    const int w = t >> 6;                            // 0..7
    const int ocl = w & 1, ks = w >> 1;              // 2 ocgrp x 4 ksplit
    const int lane = t & 63;
    const int l15 = t & 15, l4 = (t >> 4) & 3;
    const int tile = blockIdx.x;
    const int ty0 = (tile / 12) * 4, tx0 = (tile % 12) * 4;
    const int b = blockIdx.z;
    const int ocb = blockIdx.y * 32 + ocl * 16;
    const int py = ty0 + (l15 >> 2), pxx = tx0 + (l15 & 3);
    const u16* inb = in_t + (size_t)b * HWS * CIN;

    for (int i = t; i < 36 * (CIN / 8); i += 512) {
        int c8 = i % (CIN / 8); int spx = i / (CIN / 8);
        int gy = ty0 - 1 + spx / 6, gx = tx0 - 1 + spx % 6;
        uint4 v = make_uint4(0, 0, 0, 0);
        if ((unsigned)gy < 48u && (unsigned)gx < 48u)
            v = *reinterpret_cast<const uint4*>(&inb[(size_t)(gy * 48 + gx) * CIN + c8 * 8]);
        *reinterpret_cast<uint4*>(&tile_in[spx * CP + c8 * 8]) = v;
    }
    __syncthreads();

    f32x4 acc = {0, 0, 0, 0};
    constexpr int KB = CIN / 32;
    const int lpy = l15 >> 2, lpx = l15 & 3;

    __builtin_amdgcn_s_setprio(1);
#define CONV_BODY(US, UE)                                                             \
    _Pragma("unroll")                                                                 \
    for (int u = (US); u < (UE); ++u) {                                               \
        const int q = u / KB, kb = u % KB;                                            \
        const int spx = (lpy + q / 3) * 6 + (lpx + q % 3);                            \
        f16x8 B = *reinterpret_cast<const f16x8*>(&tile_in[spx * CP + kb * 32 + l4 * 8]); \
        f16x8 A = *reinterpret_cast<const f16x8*>(                                    \
            wq + ((size_t)q * 64 + ocb + l15) * CIN + kb * 32 + l4 * 8);              \
        acc = __builtin_amdgcn_mfma_f32_16x16x32_f16(A, B, acc, 0, 0, 0);             \
    }
    if (ks == 0)      { CONV_BODY(0,  U0) }
    else if (ks == 1) { CONV_BODY(U0, U1) }
    else if (ks == 2) { CONV_BODY(U1, U2) }
    else              { CONV_BODY(U2, UT) }
#undef CONV_BODY
    __builtin_amdgcn_s_setprio(0);

    if (ks) {
#pragma unroll
        for (int r = 0; r < 4; ++r)
            red[((ks - 1) * 2 + ocl) * 256 + r * 64 + lane] = acc[r];
    }
    __syncthreads();
    if (!ks) {
#pragma unroll
        for (int r = 0; r < 4; ++r) {
            float v = acc[r];
#pragma unroll
            for (int j = 0; j < 3; ++j)
                v += red[(j * 2 + ocl) * 256 + r * 64 + lane];
            int oc = ocb + l4 * 4 + r;
            v += bias[oc];
            if (LRELU) v = (v >= 0.f) ? v : 0.2f * v;
            out_t[((size_t)(b * HWS + py * 48 + pxx)) * 64 + oc] =
                __half_as_ushort(__float2half_rn(v));
        }
    }
}

// ---------------- fp16 MFMA 3x3 conv (conv4: 432 oc, f32 out), 4 waves, LDS-staged tile ----------------
template<int CIN, int OC, int OCP, bool LRELU>
__global__ __launch_bounds__(256) void conv_mfma(const u16* __restrict__ in_t,
                                                 const u16* __restrict__ wq,
                                                 const float* __restrict__ bias,
                                                 float* __restrict__ out_f) {
    constexpr int CP = CIN + 8;
    __shared__ u16 tile_in[36 * CP];
    const int t = threadIdx.x;
    const int wv = __builtin_amdgcn_readfirstlane(t >> 6);
    const int l15 = t & 15, l4 = (t >> 4) & 3;
    const int tile = blockIdx.x;
    const int ty0 = (tile / 12) * 4, tx0 = (tile % 12) * 4;
    const int ocb = blockIdx.y * 64 + wv * 16;
    const int b = blockIdx.z;
    const int py = ty0 + (l15 >> 2), pxx = tx0 + (l15 & 3);
    const u16* inb = in_t + (size_t)b * HWS * CIN;

    for (int i = t; i < 36 * (CIN / 8); i += 256) {
        int c8 = i % (CIN / 8); int spx = i / (CIN / 8);
        int gy = ty0 - 1 + spx / 6, gx = tx0 - 1 + spx % 6;
        uint4 v = make_uint4(0, 0, 0, 0);
        if ((unsigned)gy < 48u && (unsigned)gx < 48u)
            v = *reinterpret_cast<const uint4*>(&inb[(size_t)(gy * 48 + gx) * CIN + c8 * 8]);
        *reinterpret_cast<uint4*>(&tile_in[spx * CP + c8 * 8]) = v;
    }
    __syncthreads();

    f32x4 acc = {0, 0, 0, 0};
    const int lpy = l15 >> 2, lpx = l15 & 3;
    __builtin_amdgcn_s_setprio(1);
#pragma unroll
    for (int q = 0; q < 9; ++q) {
        const int spx = (lpy + q / 3) * 6 + (lpx + q % 3);
#pragma unroll
        for (int kb = 0; kb < CIN / 32; ++kb) {
            f16x8 B = *reinterpret_cast<const f16x8*>(&tile_in[spx * CP + kb * 32 + l4 * 8]);
            f16x8 A = *reinterpret_cast<const f16x8*>(
                wq + ((size_t)q * OCP + ocb + l15) * CIN + kb * 32 + l4 * 8);
            acc = __builtin_amdgcn_mfma_f32_16x16x32_f16(A, B, acc, 0, 0, 0);
        }
    }
    __builtin_amdgcn_s_setprio(0);
#pragma unroll
    for (int r = 0; r < 4; ++r) {
        int oc = ocb + l4 * 4 + r;
        float v = acc[r] + ((oc < OC) ? bias[oc] : 0.f);
        if (LRELU) v = (v >= 0.f) ? v : 0.2f * v;
        if (oc < OC) out_f[((size_t)(b * OC + oc)) * HWS + py * 48 + pxx] = v;
    }
}

// ---------------- deform (R17 exact): R9 skeleton + T14 + setprio + XCD swizzle + conflict-free val ----------------
__global__ __launch_bounds__(512) void deform_mfma(
    const u16* __restrict__ xg, const float* __restrict__ flow,
    const float* __restrict__ a4, const u16* __restrict__ wA,
    const float* __restrict__ bias, float* __restrict__ out)
{
    __shared__ u16 val[2][64 * VSTR];
    __shared__ float a4t[2][27 * 16];
    __shared__ float flds[2][128];
    __shared__ float rw[4][64];
    __shared__ int rb[64];
    const int t = threadIdx.x;
    const int traw = blockIdx.x;
    const int tile = (traw & 7) * 72 + (traw >> 3);
    const int b = blockIdx.y;
    const int ty0 = (tile / 24) * 8, tx0 = (tile % 24) * 8;
    const int lane = t & 63;
    const int og = __builtin_amdgcn_readfirstlane(t >> 6);
    const int l15 = lane & 15, l4 = lane >> 4;
    const int ys0 = (ty0 >> 2) - 1, xs0 = (tx0 >> 2) - 1;

    f32x4 acc[4];
#pragma unroll
    for (int n = 0; n < 4; ++n) acc[n] = (f32x4){0.f, 0.f, 0.f, 0.f};

    int sg_y = 0, sg_x = 0, sg_ch = 0;
    if (t < 432) {
        int ch = t >> 4, idx = t & 15;
        sg_y = min(max(ys0 + (idx >> 2), 0), 47);
        sg_x = min(max(xs0 + (idx & 3), 0), 47);
        sg_ch = ch;
    }

    if (t < 64) {
        int p = t;
        int y = ty0 + (p >> 3), xx = tx0 + (p & 7);
        float ysf = fminf(fmaxf((y + 0.5f) * 0.25f - 0.5f, 0.f), 47.f);
        float xsf = fminf(fmaxf((xx + 0.5f) * 0.25f - 0.5f, 0.f), 47.f);
        int ry0 = (int)ysf, rx0 = (int)xsf;
        float fy = ysf - (float)ry0, fx = xsf - (float)rx0;
        rb[p] = (ry0 - ys0) * 4 + (rx0 - xs0);
        rw[0][p] = (1.f - fy) * (1.f - fx);
        rw[1][p] = (1.f - fy) * fx;
        rw[2][p] = fy * (1.f - fx);
        rw[3][p] = fy * fx;
    }
    if (t < 384) {
        int bb = (t >= 192) ? 1 : 0; int j = t - bb * 192;
        int row = j / 3, un = 9 + j % 3;
        uint2 z = make_uint2(0, 0);
        *reinterpret_cast<uint2*>(&val[bb][row * VSTR + un * 8]) = z;
        *reinterpret_cast<uint2*>(&val[bb][row * VSTR + un * 8 + 4]) = z;
    }

    const float* a4b = a4 + (size_t)b * C4 * HWS;
    const float* flb = flow + (size_t)b * 32 * HW;
    const u16* xgb0 = xg + (size_t)b * DG_ * HW * 8;

#define STAGE_LOAD(gg, ra, rf) do {                                                 \
    const int gk = (gg);                                                            \
    if (t < 432) {                                                                  \
        int a4ch = (sg_ch < 18) ? (gk * 18 + sg_ch) : (288 + gk * 9 + (sg_ch - 18));\
        (ra) = a4b[(size_t)a4ch * HWS + sg_y * 48 + sg_x];                          \
    }                                                                               \
    if (t < 128) {                                                                  \
        int comp = t >> 6, p = t & 63;                                              \
        int y = ty0 + (p >> 3), xx = tx0 + (p & 7);                                 \
        (rf) = flb[(size_t)(2 * gk + 1 - comp) * HW + y * WW + xx];                 \
    }                                                                               \
} while (0)

#define STAGE_WRITE(bb, ra, rf) do {                                                \
    if (t < 432) a4t[bb][t] = (ra);                                                 \
    if (t < 128) flds[bb][t] = (rf);                                                \
} while (0)

#define PH12(gg, bb) do {                                                           \
    const u16* xgb = xgb0 + (size_t)(gg) * HW * 8;                                  \
    for (int i = t; i < 576; i += 512) {                                            \
        int k = i >> 6, p = i & 63;                                                 \
        int y = ty0 + (p >> 3), xx = tx0 + (p & 7);                                 \
        int base = rb[p];                                                           \
        float r00 = rw[0][p], r01 = rw[1][p], r10 = rw[2][p], r11 = rw[3][p];       \
        const float* A = &a4t[bb][0];                                               \
        float sdy = A[(2*k)*16+base]*r00 + A[(2*k)*16+base+1]*r01                   \
                  + A[(2*k)*16+base+4]*r10 + A[(2*k)*16+base+5]*r11;                \
        float sdx = A[(2*k+1)*16+base]*r00 + A[(2*k+1)*16+base+1]*r01               \
                  + A[(2*k+1)*16+base+4]*r10 + A[(2*k+1)*16+base+5]*r11;            \
        float sm  = A[(18+k)*16+base]*r00 + A[(18+k)*16+base+1]*r01                 \
                  + A[(18+k)*16+base+4]*r10 + A[(18+k)*16+base+5]*r11;              \
        float dyv = 5.f * tanh_fast(sdy) + flds[bb][p];                             \
        float dxv = 5.f * tanh_fast(sdx) + flds[bb][64 + p];                        \
        float m = sigmoid_fast(sm);                                                 \
        float fpy = (float)(y + (k / 3) - 1) + dyv;                                 \
        float fpx = (float)(xx + (k % 3) - 1) + dxv;                                \
        float y0f = floorf(fpy), x0f = floorf(fpx);                                 \
        int gy0 = (int)y0f, gx0 = (int)x0f;                                         \
        int gy1 = gy0 + 1, gx1 = gx0 + 1;                                           \
        float wy = fpy - y0f, wx = fpx - x0f;                                       \
        bool by0 = (unsigned)gy0 < (unsigned)HH, by1 = (unsigned)gy1 < (unsigned)HH;\
        bool bx0 = (unsigned)gx0 < (unsigned)WW, bx1 = (unsigned)gx1 < (unsigned)WW;\
        int y0c = min(max(gy0, 0), HH - 1), y1c = min(max(gy1, 0), HH - 1);         \
        int x0c = min(max(gx0, 0), WW - 1), x1c = min(max(gx1, 0), WW - 1);         \
        float w00 = (by0 && bx0) ? (1.f - wy) * (1.f - wx) * m : 0.f;               \
        float w01 = (by0 && bx1) ? (1.f - wy) * wx * m : 0.f;                       \
        float w10 = (by1 && bx0) ? wy * (1.f - wx) * m : 0.f;                       \
        float w11 = (by1 && bx1) ? wy * wx * m : 0.f;                               \
        uint4 v00 = *reinterpret_cast<const uint4*>(&xgb[(size_t)(y0c * WW + x0c) * 8]); \
        uint4 v01 = *reinterpret_cast<const uint4*>(&xgb[(size_t)(y0c * WW + x1c) * 8]); \
        uint4 v10 = *reinterpret_cast<const uint4*>(&xgb[(size_t)(y1c * WW + x0c) * 8]); \
        uint4 v11 = *reinterpret_cast<const uint4*>(&xgb[(size_t)(y1c * WW + x1c) * 8]); \
        const __half2* h00 = reinterpret_cast<const __half2*>(&v00);                \
        const __half2* h01 = reinterpret_cast<const __half2*>(&v01);                \
        const __half2* h10 = reinterpret_cast<const __half2*>(&v10);                \
        const __half2* h11 = reinterpret_cast<const __half2*>(&v11);                \
        __half hw00 = __float2half_rn(w00), hw01 = __float2half_rn(w01);            \
        __half hw10 = __float2half_rn(w10), hw11 = __float2half_rn(w11);            \
        __half2 W00{hw00, hw00}, W01{hw01, hw01}, W10{hw10, hw10}, W11{hw11, hw11}; \
        union { __half2 h2[4]; uint2 u2[2]; } uu;                                   \
        _Pragma("unroll")                                                           \
        for (int cc = 0; cc < 4; ++cc)                                              \
            uu.h2[cc] = __hfma2(h00[cc], W00, __hfma2(h01[cc], W01,                 \
                        __hfma2(h10[cc], W10, __hmul2(h11[cc], W11))));             \
        *reinterpret_cast<uint2*>(&val[bb][p * VSTR + k * 8]) = uu.u2[0];           \
        *reinterpret_cast<uint2*>(&val[bb][p * VSTR + k * 8 + 4]) = uu.u2[1];       \
    }                                                                               \
} while (0)

    {
        float ra = 0.f, rf = 0.f;
        STAGE_LOAD(0, ra, rf);
        STAGE_WRITE(0, ra, rf);
    }
    __syncthreads();

    for (int g = 0; g < DG_; ++g) {
        const int buf = g & 1;
        float ra = 0.f, rf = 0.f;
        if (g < 15) STAGE_LOAD(g + 1, ra, rf);
        PH12(g, buf);
        if (g < 15) STAGE_WRITE(buf ^ 1, ra, rf);
        __syncthreads();
        const u16* wg = wA + (size_t)(og * 16) * 1536 + g * 96;
        __builtin_amdgcn_s_setprio(1);
#pragma unroll
        for (int kb = 0; kb < 3; ++kb) {
            f16x8 a = *reinterpret_cast<const f16x8*>(wg + (size_t)l15 * 1536 + kb * 32 + l4 * 8);
#pragma unroll
            for (int nf = 0; nf < 4; ++nf) {
                int row = nf * 16 + l15;
                union { uint2 u2[2]; f16x8 v; } bf;
                bf.u2[0] = *reinterpret_cast<const uint2*>(&val[buf][row * VSTR + kb * 32 + l4 * 8]);
                bf.u2[1] = *reinterpret_cast<const uint2*>(&val[buf][row * VSTR + kb * 32 + l4 * 8 + 4]);
                acc[nf] = __builtin_amdgcn_mfma_f32_16x16x32_f16(a, bf.v, acc[nf], 0, 0, 0);
            }
        }
        __builtin_amdgcn_s_setprio(0);
    }
#undef STAGE_LOAD
#undef STAGE_WRITE
#undef PH12
#pragma unroll
    for (int nf = 0; nf < 4; ++nf) {
        int pix = nf * 16 + l15;
        int py = ty0 + (pix >> 3), px = tx0 + (pix & 7);
#pragma unroll
        for (int r = 0; r < 4; ++r) {
            int o = og * 16 + l4 * 4 + r;
            out[((size_t)(b * COUT_D + o) * HH + py) * WW + px] = acc[nf][r] + bias[o];
        }
    }
}

extern "C" void kernel_launch(void* const* d_in, const int* in_sizes, int n_in,
                              void* d_out, int out_size, void* d_ws, size_t ws_size,
                              hipStream_t stream) {
    const float* x    = (const float*)d_in[0];
    const float* flow = (const float*)d_in[1];
    const float* addf = (const float*)d_in[2];
    const float* w1   = (const float*)d_in[3];
    const float* b1   = (const float*)d_in[4];
    const float* w2   = (const float*)d_in[5];
    const float* b2   = (const float*)d_in[6];
    const float* w3   = (const float*)d_in[7];
    const float* b3   = (const float*)d_in[8];
    const float* w4   = (const float*)d_in[9];
    const float* b4   = (const float*)d_in[10];
    const float* wgt  = (const float*)d_in[11];
    const float* bias = (const float*)d_in[12];
    float* out = (float*)d_out;
    float* ws = (float*)d_ws;

    u16*  pool_t = (u16*)ws;                         // 737,280 u16 (fp16)
    u16*  c1     = pool_t + 737280;                  // 294,912 u16
    u16*  c2     = c1 + 294912;                      // 294,912 u16
    u16*  c3     = c1;                               // alias (c1 dead after conv2)
    float* a4    = (float*)(c2 + 294912);            // 1,990,656 f32
    u16*  wq1    = (u16*)(a4 + 1990656);             // 92,160 u16
    u16*  wq2    = wq1 + 92160;                      // 36,864
    u16*  wq3    = wq2 + 36864;                      // 36,864
    u16*  wq4    = wq3 + 36864;                      // 258,048
    u16*  wA     = wq4 + 258048;                     // 196,608 (fp16)
    u16*  xg     = wA + 196608;                      // 9,437,184 (fp16)

    mega_prep_kernel<<<9912, 256, 0, stream>>>(w1, w2, w3, w4, wgt, x, flow, addf,
                                               wq1, wq2, wq3, wq4, wA, xg, pool_t);

    conv_ks<160, 12, 23, 34, 45, true><<<dim3(144, 2, 2), 512, 0, stream>>>(pool_t, wq1, b1, c1);
    conv_ks<64,  5,  10, 14, 18, true><<<dim3(144, 2, 2), 512, 0, stream>>>(c1, wq2, b2, c2);
    conv_ks<64,  5,  10, 14, 18, true><<<dim3(144, 2, 2), 512, 0, stream>>>(c2, wq3, b3, c3);
    conv_mfma<64, 432, 448, false><<<dim3(144, 7, 2), 256, 0, stream>>>(c3, wq4, b4, a4);

    deform_mfma<<<dim3(576, 2), 512, 0, stream>>>(xg, flow, a4, wA, bias, out);
}